// Round 12
// baseline (318.477 us; speedup 1.0000x reference)
//
#include <hip/hip_runtime.h>
#include <hip/hip_bf16.h>
#include <stdint.h>

#define NH 12
#define DHD 64
#define DM 768
#define BB 32
#define SS 512
#define GG 16
#define NCTX 8
#define RBATCH 4
#define NSPLIT 4
#define OUTG_OFF ((size_t)BB * SS * DM)

#define XROWS 16512            // 16384 hs + 64 gte + 64 zero pad
#define NALL 2304              // 3*768 concat Q|K|V output cols
#define NX8 (XROWS * DM / 8)
#define NB8 (NALL / 8)
#define NM8 (BB * SS / 8)

#define LOG2E 1.4426950408889634f
#define QSCALE 0.18033688011112042f   // 0.125 * log2(e)

typedef __bf16 bf16x8 __attribute__((ext_vector_type(8)));
typedef float f32x4 __attribute__((ext_vector_type(4)));
typedef float f32x16 __attribute__((ext_vector_type(16)));

__device__ __forceinline__ float b2f(unsigned short u) {
    union { unsigned int i; float f; } x;
    x.i = ((unsigned int)u) << 16;
    return x.f;
}
__device__ __forceinline__ unsigned short f2b(float f) {
    __hip_bfloat16 h = __float2bfloat16(f);
    return *reinterpret_cast<unsigned short*>(&h);
}
__device__ __forceinline__ unsigned int pk2(float a, float b) {
    return ((unsigned int)f2b(b) << 16) | (unsigned int)f2b(a);
}
__device__ __forceinline__ float ex2(float x) {
    return __builtin_amdgcn_exp2f(x);
}
__device__ __forceinline__ float ldv(const void* p, size_t i, int isf32) {
    return isf32 ? ((const float*)p)[i] : b2f(((const unsigned short*)p)[i]);
}
__device__ __forceinline__ void stv(void* p, size_t i, int isf32, float v) {
    if (isf32) ((float*)p)[i] = v;
    else       ((unsigned short*)p)[i] = f2b(v);
}
// async global->LDS, 16B per lane; LDS dest = wave-uniform base + lane*16
__device__ __forceinline__ void async_cp16(const unsigned short* g, unsigned short* l) {
    __builtin_amdgcn_global_load_lds(
        (const __attribute__((address_space(1))) unsigned int*)g,
        (__attribute__((address_space(3))) unsigned int*)l, 16, 0, 0);
}

// Transposed V store: rows (vr, vr+1) x cols [scc, scc+8) packed pairwise with
// v_perm into u32 writes. Layout (u16 view): Vt[d*2*ldq + swz8 + (key&7)],
// swz8 = ((key>>3)^((d>>3)&7))<<3 — identical to the scalar-store layout.
__device__ __forceinline__ void vt_pair_store(unsigned int* Vt32, int vr, int scc,
                                              uint4 a, uint4 b, int ldq) {
    const unsigned int* au = (const unsigned int*)&a;
    const unsigned int* bu = (const unsigned int*)&b;
    #pragma unroll
    for (int i = 0; i < 4; i++) {
        const int d0 = scc + 2 * i;
        const int swz = ((vr >> 3) ^ ((d0 >> 3) & 7));
        const int i32 = d0 * ldq + (swz << 2) + ((vr & 7) >> 1);
        Vt32[i32]       = __builtin_amdgcn_perm(bu[i], au[i], 0x05040100u);
        Vt32[i32 + ldq] = __builtin_amdgcn_perm(bu[i], au[i], 0x07060302u);
    }
}

// ---------------------------------------------------------------------------
// cvt_xw: fused cvt_x + cvt_w, with INLINE per-block dtype detection on Wq
// (sigma=0.02, never exactly 0). Block 0 writes *flag and zeroes the
// split-k merge counters (48 ints) for attn_fused.
// Blocks [0, CVT_XBLKS): X_bf16[16512][768] = [hs ; gte ; zeros], bias_all,
// wmask pre-scaled by log2(e). Blocks [CVT_XBLKS, +432): Wt transpose.
// ---------------------------------------------------------------------------
#define CVT_ITEMS (NX8 + NB8 + NM8)
#define CVT_XBLKS ((CVT_ITEMS + 255) / 256)
#define CVT_WBLKS (12 * 36)
__global__ __launch_bounds__(256) void cvt_xw(
    const void* __restrict__ hs, const void* __restrict__ gte,
    const void* __restrict__ bq, const void* __restrict__ bk,
    const void* __restrict__ bv, const void* __restrict__ mask,
    const void* __restrict__ Wq, const void* __restrict__ Wk,
    const void* __restrict__ Wv,
    unsigned short* __restrict__ Xb, unsigned short* __restrict__ b_all,
    unsigned short* __restrict__ wmask, unsigned short* __restrict__ Wt,
    int* __restrict__ flag, int* __restrict__ cnt)
{
    __shared__ float T[64][65];
    __shared__ int redhi, redzz;
    const int tid = threadIdx.x;

    // inline dtype detection (L2-hot after the first block; ~16 dword loads)
    {
        const unsigned short* wq16 = (const unsigned short*)Wq;
        int lh = 0, lz = 0;
        for (int i = tid; i < 4096; i += 256) {
            unsigned short u = wq16[2 * i];
            if (((u >> 7) & 0xFF) >= 130) lh++;
            if (u == 0) lz++;
        }
        if (tid == 0) { redhi = 0; redzz = 0; }
        __syncthreads();
        #pragma unroll
        for (int off = 32; off; off >>= 1) {
            lh += __shfl_down(lh, off, 64);
            lz += __shfl_down(lz, off, 64);
        }
        if ((tid & 63) == 0) { atomicAdd(&redhi, lh); atomicAdd(&redzz, lz); }
        __syncthreads();
    }
    const int isf32 = (redhi > 512 || redzz > 3500) ? 1 : 0;
    if (blockIdx.x == 0) {
        if (tid == 0) *flag = isf32;
        if (tid < NH * RBATCH) cnt[tid] = 0;   // split-k merge counters
    }

    if (blockIdx.x < CVT_XBLKS) {
        const int e = blockIdx.x * 256 + tid;
        if (e < NX8) {
            const int base = e * 8;
            const int row = base / DM, col = base % DM;
            unsigned short o8[8];
            if (row < 16384) {
                if (isf32) {
                    float4 a = ((const float4*)hs)[e * 2];
                    float4 c = ((const float4*)hs)[e * 2 + 1];
                    o8[0]=f2b(a.x); o8[1]=f2b(a.y); o8[2]=f2b(a.z); o8[3]=f2b(a.w);
                    o8[4]=f2b(c.x); o8[5]=f2b(c.y); o8[6]=f2b(c.z); o8[7]=f2b(c.w);
                } else {
                    *(uint4*)o8 = ((const uint4*)hs)[e];
                }
            } else if (row < 16448) {
                size_t soff = (size_t)(row - 16384) * DM + col;
                #pragma unroll
                for (int i = 0; i < 8; i++) o8[i] = f2b(ldv(gte, soff + i, isf32));
            } else {
                #pragma unroll
                for (int i = 0; i < 8; i++) o8[i] = 0;
            }
            *(uint4*)&Xb[base] = *(const uint4*)o8;
        } else if (e < NX8 + NB8) {
            const int i0 = (e - NX8) * 8;
            #pragma unroll
            for (int i = 0; i < 8; i++) {
                int ng = i0 + i;
                int z = ng / DM;
                const void* src = (z == 0) ? bq : (z == 1) ? bk : bv;
                b_all[ng] = f2b(ldv(src, ng % DM, isf32));
            }
        } else if (e < NX8 + NB8 + NM8) {
            const int i0 = (e - NX8 - NB8) * 8;
            #pragma unroll
            for (int i = 0; i < 8; i++)
                wmask[i0 + i] = f2b(ldv(mask, i0 + i, isf32) * LOG2E);
        }
    } else {
        const int widx = blockIdx.x - CVT_XBLKS;
        const int kt = widx % 12;
        const int ngt = widx / 12;
        const int z = ngt / 12, nt = ngt % 12;
        const void* W = (z == 0) ? Wq : (z == 1) ? Wk : Wv;

        for (int jj = 0; jj < 16; jj++) {
            int el = tid + jj * 256;
            int r = el >> 6, c = el & 63;
            T[r][c] = ldv(W, (size_t)(kt * 64 + r) * DM + nt * 64 + c, isf32);
        }
        __syncthreads();
        for (int jj = 0; jj < 16; jj++) {
            int el = tid + jj * 256;
            int rn = el >> 6, ck = el & 63;
            Wt[(size_t)(z * DM + nt * 64 + rn) * DM + kt * 64 + ck] = f2b(T[ck][rn]);
        }
    }
}

// ---------------------------------------------------------------------------
// Fused QKV GEMM v4 (round-5 proven, 103.3 us): 128x128 tile, pair-window
// double buffer — each window stages TWO BK=32 k-tiles (8 async_cp16) and
// computes 32 MFMAs, 12 __syncthreads drains instead of 24.
// XCD-chunked nt-fast swizzle; operand-swapped MFMA epilogue (uint2 stores).
// ---------------------------------------------------------------------------
#define QKV_NWG (129 * 18)
__global__ __launch_bounds__(256) void qkv_gemm(
    const unsigned short* __restrict__ Xb,
    const unsigned short* __restrict__ Wt,
    const unsigned short* __restrict__ b_all,
    unsigned short* __restrict__ q, unsigned short* __restrict__ kk_,
    unsigned short* __restrict__ v,
    unsigned short* __restrict__ gq, unsigned short* __restrict__ gk,
    unsigned short* __restrict__ gv)
{
    __shared__ __align__(16) unsigned short As[2][2][128 * 32];
    __shared__ __align__(16) unsigned short Bs[2][2][128 * 32];

    const int orig = blockIdx.x;
    const int q8 = QKV_NWG >> 3, r8 = QKV_NWG & 7;
    const int xcd = orig & 7, lin = orig >> 3;
    const int swz = (xcd < r8 ? xcd * (q8 + 1) : r8 * (q8 + 1) + (xcd - r8) * q8) + lin;
    const int mt = swz / 18, nt = swz - mt * 18;

    const int tid = threadIdx.x;
    const int wave = tid >> 6, lane = tid & 63;
    const int quad = lane >> 4, l16 = lane & 15;
    const int wm = wave & 1, wn = wave >> 1;
    const int z = nt / 6;
    unsigned short* YL = (z == 0) ? q : (z == 1) ? kk_ : v;
    unsigned short* YG = (z == 0) ? gq : (z == 1) ? gk : gv;
    const float qsc = (z == 0) ? QSCALE : 1.0f;

    const int sr = tid >> 2, sc = (tid & 3) * 8;  // LDS slot = tid*16B

    const unsigned short* Arow0 = &Xb[(size_t)(mt * 128 + sr) * DM + sc];
    const unsigned short* Arow1 = Arow0 + (size_t)64 * DM;
    const unsigned short* Brow0 = &Wt[(size_t)(nt * 128 + sr) * DM + sc];
    const unsigned short* Brow1 = Brow0 + (size_t)64 * DM;

    f32x4 acc[4][4];
    #pragma unroll
    for (int i = 0; i < 4; i++)
        for (int j = 0; j < 4; j++)
            for (int r = 0; r < 4; r++) acc[i][j][r] = 0.f;

    // stage k-tile pair p (tiles 2p, 2p+1) into buffer bb
#define QKV_STAGE_PAIR(p, bb) do {                                       \
        const int k0_ = (p) * 64;                                        \
        async_cp16(Arow0 + k0_,      &As[(bb)][0][wave * 512]);          \
        async_cp16(Arow1 + k0_,      &As[(bb)][0][2048 + wave * 512]);   \
        async_cp16(Brow0 + k0_,      &Bs[(bb)][0][wave * 512]);          \
        async_cp16(Brow1 + k0_,      &Bs[(bb)][0][2048 + wave * 512]);   \
        async_cp16(Arow0 + k0_ + 32, &As[(bb)][1][wave * 512]);          \
        async_cp16(Arow1 + k0_ + 32, &As[(bb)][1][2048 + wave * 512]);   \
        async_cp16(Brow0 + k0_ + 32, &Bs[(bb)][1][wave * 512]);          \
        async_cp16(Brow1 + k0_ + 32, &Bs[(bb)][1][2048 + wave * 512]);   \
    } while (0)

    // prologue: stage pair 0 into buffer 0
    QKV_STAGE_PAIR(0, 0);
    __syncthreads();

    int cur = 0;
    for (int p = 0; p < 12; p++) {
        // prefetch next pair into the other buffer (hidden under 32 MFMAs)
        if (p < 11) QKV_STAGE_PAIR(p + 1, cur ^ 1);

        #pragma unroll
        for (int sub = 0; sub < 2; sub++) {
            bf16x8 af[4], bf[4];
            #pragma unroll
            for (int ib = 0; ib < 4; ib++)
                af[ib] = *(const bf16x8*)&As[cur][sub][(wm * 64 + ib * 16 + l16) * 32 + quad * 8];
            #pragma unroll
            for (int jb = 0; jb < 4; jb++)
                bf[jb] = *(const bf16x8*)&Bs[cur][sub][(wn * 64 + jb * 16 + l16) * 32 + quad * 8];
            // operand-swapped: C rows = output channels (ng), C cols = X rows (m)
            #pragma unroll
            for (int ib = 0; ib < 4; ib++)
                #pragma unroll
                for (int jb = 0; jb < 4; jb++)
                    acc[ib][jb] = __builtin_amdgcn_mfma_f32_16x16x32_bf16(
                        bf[jb], af[ib], acc[ib][jb], 0, 0, 0);
        }

        if (p < 11) __syncthreads();
        cur ^= 1;
    }
#undef QKV_STAGE_PAIR

    // epilogue: lane holds m = ...+l16 (fixed), 4 consecutive ng per acc reg
    #pragma unroll
    for (int ib = 0; ib < 4; ib++) {
        const int m = mt * 128 + wm * 64 + ib * 16 + l16;
        if (m >= 16448) continue;
        const bool loc = (m < 16384);
        const int b = m >> 9, s = m & 511;
        const int gl = m - 16384;
        const int rbx = gl >> 4, g = gl & 15;
        #pragma unroll
        for (int jb = 0; jb < 4; jb++) {
            const int ng0 = nt * 128 + wn * 64 + jb * 16 + quad * 4;
            const int o = ng0 - z * DM;
            const int h = o >> 6, dh0 = o & 63;
            const uint2 bu = *(const uint2*)&b_all[ng0];
            const unsigned short* bp = (const unsigned short*)&bu;
            const float y0 = (acc[ib][jb][0] + b2f(bp[0])) * qsc;
            const float y1 = (acc[ib][jb][1] + b2f(bp[1])) * qsc;
            const float y2 = (acc[ib][jb][2] + b2f(bp[2])) * qsc;
            const float y3 = (acc[ib][jb][3] + b2f(bp[3])) * qsc;
            uint2 o2;
            o2.x = pk2(y0, y1);
            o2.y = pk2(y2, y3);
            if (loc) {
                *(uint2*)&YL[(((size_t)b * NH + h) * SS + s) * DHD + dh0] = o2;
            } else {
                *(uint2*)&YG[(((size_t)rbx * NH + h) * GG + g) * DHD + dh0] = o2;
            }
        }
    }
}

// ---------------------------------------------------------------------------
// attn_fused: gsplit blocks [0, GS_NWG) + local blocks [GS_NWG, +AL_NWG).
// Independent sub-kernels fused for concurrency (round-10: -16 us). NEW:
// the LAST gsplit block per (h,rb) (split-k semaphore: threadfence +
// device-scope atomicAdd, G16/m20) performs the 4-partial merge inline —
// the separate attn_gmerge dispatch is gone.
// ---------------------------------------------------------------------------
#define GS_NWG (NH * RBATCH * NSPLIT)   // 192
#define AL_NWG (4 * NH * BB)            // 1536, divisible by 8
__global__ __launch_bounds__(256) void attn_fused(
    const unsigned short* __restrict__ q,
    const unsigned short* __restrict__ k,
    const unsigned short* __restrict__ v,
    const unsigned short* __restrict__ gq,
    const unsigned short* __restrict__ gk,
    const unsigned short* __restrict__ gv,
    const unsigned short* __restrict__ wmask,
    const int* __restrict__ flag,
    void* __restrict__ out,
    float* __restrict__ Opart, float* __restrict__ Mpart,
    float* __restrict__ Lpart, int* __restrict__ cnt)
{
    __shared__ __align__(16) unsigned short SMEM[20480];   // 40 KiB union
    __shared__ int lastflag;

    const int tid = threadIdx.x, wave = tid >> 6, lane = tid & 63;
    const int sr = tid >> 3, scc = (tid & 7) * 8;
    const int vr = sr * 2;
    const int agc = (((lane & 7) ^ ((lane >> 3) & 7)) << 3);
    const int arow = 8 * wave + (lane >> 3);

    if (blockIdx.x < GS_NWG) {
        // ================= gsplit path (round-8 body, NSPLIT=4) =============
        unsigned short* Ks = SMEM;                    // 128*64
        unsigned short* Vt = SMEM + 8192;             // 64*128
        unsigned short* Ps = SMEM + 16384;            // 4*16*64
        unsigned int* Vt32 = (unsigned int*)Vt;

        const int idx = blockIdx.x;
        const int h = idx % NH;
        const int rb = (idx / NH) % RBATCH;
        const int sp = idx / (NH * RBATCH);
        const int quad = lane >> 4, l16 = lane & 15;

        const size_t gbh = (size_t)rb * NH + h;
        const unsigned short* gqp = gq + gbh * GG * DHD;
        const unsigned short* gkp = gk + gbh * GG * DHD;
        const unsigned short* gvp = gv + gbh * GG * DHD;

        bf16x8 aq[2];
        aq[0] = *(const bf16x8*)&gqp[l16 * DHD + quad * 8];
        aq[1] = *(const bf16x8*)&gqp[l16 * DHD + 32 + quad * 8];

        f32x4 oacc[4];
        #pragma unroll
        for (int db = 0; db < 4; db++)
            for (int r = 0; r < 4; r++) oacc[db][r] = 0.f;
        float m_s = -1e30f, l_s = 0.f;

        unsigned short* myP = &Ps[wave * 1024];

        const int ntt = (sp == 0) ? 9 : 8;
        for (int ti = 0; ti < ntt; ti++) {
            const bool gtile = (sp == 0 && ti == 0);
            int cb = 0, soff = 0;
            __syncthreads();
            if (gtile) {
                if (sr < 16) {
                    uint4 kx = *(const uint4*)&gkp[sr * DHD + scc];
                    *(uint4*)&Ks[sr * 64 + (((scc >> 3) ^ (sr & 7)) << 3)] = kx;
                    uint4 va = {0, 0, 0, 0}, vb = {0, 0, 0, 0};
                    if (sr < 8) {
                        va = *(const uint4*)&gvp[vr * DHD + scc];
                        vb = *(const uint4*)&gvp[(vr + 1) * DHD + scc];
                    }
                    vt_pair_store(Vt32, vr, scc, va, vb, 64);
                } else {
                    uint4 zz4 = {0, 0, 0, 0};
                    *(uint4*)&Ks[sr * 64 + (((scc >> 3) ^ (sr & 7)) << 3)] = zz4;
                }
            } else {
                const int kidx = sp * 1024 + (ti - ((sp == 0) ? 1 : 0)) * 128;
                cb = rb * NCTX + (kidx >> 9);
                soff = kidx & 511;
                const unsigned short* kp = k + ((size_t)cb * NH + h) * SS * DHD;
                const unsigned short* vp = v + ((size_t)cb * NH + h) * SS * DHD;
                #pragma unroll
                for (int p = 0; p < 4; p++)
                    async_cp16(&kp[(size_t)(soff + p * 32 + arow) * DHD + agc],
                               &Ks[p * 2048 + wave * 512]);
                #pragma unroll
                for (int pp = 0; pp < 2; pp++) {
                    const int vrr = vr + pp * 64;
                    uint4 va = *(const uint4*)&vp[(size_t)(soff + vrr) * DHD + scc];
                    uint4 vb = *(const uint4*)&vp[(size_t)(soff + vrr + 1) * DHD + scc];
                    vt_pair_store(Vt32, vrr, scc, va, vb, 64);
                }
            }
            __syncthreads();

            if (gtile && wave != 0) continue;

            const int nbn = gtile ? 1 : 2;
            f32x4 c[2];
            for (int hh = 0; hh < nbn; hh++) {
                f32x4 cc = {0.f, 0.f, 0.f, 0.f};
                const int key = wave * 32 + hh * 16 + l16;
                #pragma unroll
                for (int kd = 0; kd < 2; kd++) {
                    bf16x8 kf = *(const bf16x8*)&Ks[key * 64 + (((kd * 4 + quad) ^ (key & 7)) << 3)];
                    cc = __builtin_amdgcn_mfma_f32_16x16x32_bf16(kf, aq[kd], cc, 0, 0, 0);
                }
                if (!gtile) {
                    uint2 mu = *(const uint2*)&wmask[cb * SS + soff + wave * 32 + hh * 16 + quad * 4];
                    const unsigned short* mp = (const unsigned short*)&mu;
                    #pragma unroll
                    for (int r = 0; r < 4; r++)
                        cc[r] += b2f(mp[r]);
                }
                c[hh] = cc;
            }

            float mx = -1e30f;
            for (int hh = 0; hh < nbn; hh++)
                #pragma unroll
                for (int r = 0; r < 4; r++) mx = fmaxf(mx, c[hh][r]);
            mx = fmaxf(mx, __shfl_xor(mx, 16, 64));
            mx = fmaxf(mx, __shfl_xor(mx, 32, 64));
            const float mn = fmaxf(m_s, mx);
            const float alpha = ex2(m_s - mn);
            m_s = mn;
            float rs = 0.f;
            for (int hh = 0; hh < nbn; hh++)
                #pragma unroll
                for (int r = 0; r < 4; r++) {
                    float p = ex2(c[hh][r] - mn);
                    c[hh][r] = p;
                    rs += p;
                }
            rs += __shfl_xor(rs, 16, 64);
            rs += __shfl_xor(rs, 32, 64);
            l_s = l_s * alpha + rs;
            #pragma unroll
            for (int db = 0; db < 4; db++)
                for (int r = 0; r < 4; r++) oacc[db][r] *= alpha;

            for (int hh = 0; hh < nbn; hh++) {
                uint2 pw;
                pw.x = pk2(c[hh][0], c[hh][1]);
                pw.y = pk2(c[hh][2], c[hh][3]);
                const int cch = ((hh * 2 + (quad >> 1)) ^ (l16 & 7));
                *(uint2*)&myP[l16 * 64 + cch * 8 + (quad & 1) * 4] = pw;
            }
            if (nbn == 1) {
                uint2 zz2; zz2.x = 0; zz2.y = 0;
                const int cch = ((2 + (quad >> 1)) ^ (l16 & 7));
                *(uint2*)&myP[l16 * 64 + cch * 8 + (quad & 1) * 4] = zz2;
            }

            bf16x8 pf = *(const bf16x8*)&myP[l16 * 64 + ((quad ^ (l16 & 7)) << 3)];
            #pragma unroll
            for (int db = 0; db < 4; db++) {
                const int d = db * 16 + l16;
                const int kc = wave * 4 + quad;
                bf16x8 vf = *(const bf16x8*)&Vt[d * 128 + ((kc ^ ((d >> 3) & 7)) << 3)];
                oacc[db] = __builtin_amdgcn_mfma_f32_16x16x32_bf16(vf, pf, oacc[db], 0, 0, 0);
            }
        }

        // intra-block merge of 4 waves, then write split partial
        __syncthreads();
        float* Om = (float*)Ks;            // [4][16][64]
        float* Mw = (float*)Vt;            // [4][16]
        float* Lw = Mw + 64;
        const int quad2 = lane >> 4, l162 = lane & 15;
        #pragma unroll
        for (int db = 0; db < 4; db++)
            for (int r = 0; r < 4; r++)
                Om[(wave * 16 + l162) * 64 + db * 16 + quad2 * 4 + r] = oacc[db][r];
        if (quad2 == 0) {
            Mw[wave * 16 + l162] = m_s;
            Lw[wave * 16 + l162] = l_s;
        }
        __syncthreads();

        const size_t pbase = ((size_t)(sp * RBATCH + rb) * NH + h) * 1024;
        for (int e = tid; e < 1024; e += 256) {
            const int qrow = e >> 6, d = e & 63;
            float M = fmaxf(fmaxf(Mw[qrow], Mw[16 + qrow]), fmaxf(Mw[32 + qrow], Mw[48 + qrow]));
            float acc = 0.f, L = 0.f;
            #pragma unroll
            for (int w = 0; w < 4; w++) {
                float scw = ex2(Mw[w * 16 + qrow] - M);
                acc += Om[(w * 16 + qrow) * 64 + d] * scw;
                L += Lw[w * 16 + qrow] * scw;
            }
            Opart[pbase + e] = acc;
            if (d == 0) {
                Mpart[((sp * RBATCH + rb) * NH + h) * 16 + qrow] = M;
                Lpart[((sp * RBATCH + rb) * NH + h) * 16 + qrow] = L;
            }
        }

        // --- split-k semaphore: last (h,rb) arrival merges the 4 partials ---
        __syncthreads();                       // all partial stores retired
        if (tid == 0) {
            __threadfence();                   // device-scope release (L2 wb)
            const int old = atomicAdd(&cnt[rb * NH + h], 1);
            lastflag = (old == NSPLIT - 1) ? 1 : 0;
        }
        __syncthreads();
        if (lastflag) {
            if (tid == 0) __threadfence();     // device-scope acquire (L2 inv)
            __syncthreads();
            const int isf32m = *flag;
            for (int e = tid; e < 1024; e += 256) {
                const int qrow = e >> 6, d = e & 63;
                float M = -1e30f;
                #pragma unroll
                for (int spp = 0; spp < NSPLIT; spp++)
                    M = fmaxf(M, Mpart[((spp * RBATCH + rb) * NH + h) * 16 + qrow]);
                float acc2 = 0.f, L = 0.f;
                #pragma unroll
                for (int spp = 0; spp < NSPLIT; spp++) {
                    const size_t pb = ((size_t)(spp * RBATCH + rb) * NH + h);
                    float scs = ex2(Mpart[pb * 16 + qrow] - M);
                    acc2 += Opart[pb * 1024 + e] * scs;
                    L += Lpart[pb * 16 + qrow] * scs;
                }
                stv(out, OUTG_OFF + ((size_t)rb * GG + qrow) * DM + h * DHD + d,
                    isf32m, acc2 / L);
            }
        }
        return;
    }

    // ================= local path (round-8 v6 body) =========================
    unsigned short* KsBuf = SMEM;          // [2][64*64]
    unsigned short* VtBuf = SMEM + 8192;   // [2][64*64]

    const int orig = blockIdx.x - GS_NWG;
    const int swz = (orig & 7) * (AL_NWG / 8) + (orig >> 3);
    const int qt = swz & 3;
    const int hb = swz >> 2;
    const int h = hb % NH, b = hb / NH;

    const int rb = b >> 3;
    const int l31 = lane & 31, h8 = lane >> 5;
    const int isf32 = *flag;
    const int q0 = qt * 128 + wave * 32;

    const size_t bh = (size_t)b * NH + h;
    const unsigned short* qp = q + bh * SS * DHD;
    const unsigned short* kp = k + bh * SS * DHD;
    const unsigned short* vp = v + bh * SS * DHD;
    const size_t gbh = (size_t)rb * NH + h;
    const unsigned short* gkp = gk + gbh * GG * DHD;
    const unsigned short* gvp = gv + gbh * GG * DHD;

    // Q fragments (MFMA B-operand): B[k][n]: n=q=l31, k = kb*16 + h8*8 + j
    bf16x8 qf[4];
    #pragma unroll
    for (int kb = 0; kb < 4; kb++)
        qf[kb] = *(const bf16x8*)&qp[(size_t)(q0 + l31) * DHD + kb * 16 + h8 * 8];

    f32x16 oacc[2];
    #pragma unroll
    for (int mb = 0; mb < 2; mb++)
        #pragma unroll
        for (int j = 0; j < 16; j++) oacc[mb][j] = 0.f;
    float m_s = -1e30f, l_s = 0.f;

    // prologue: stage tile 0 (16 global keys + zero pad) into buffer 0
    if (sr < 16) {
        uint4 kx = *(const uint4*)&gkp[sr * DHD + scc];
        *(uint4*)&KsBuf[sr * 64 + (((scc >> 3) ^ (sr & 7)) << 3)] = kx;
    } else {
        uint4 zz4 = {0, 0, 0, 0};
        *(uint4*)&KsBuf[sr * 64 + (((scc >> 3) ^ (sr & 7)) << 3)] = zz4;
    }
    {
        uint4 va0 = {0, 0, 0, 0}, vb0 = {0, 0, 0, 0};
        if (sr < 8) {
            va0 = *(const uint4*)&gvp[vr * DHD + scc];
            vb0 = *(const uint4*)&gvp[(vr + 1) * DHD + scc];
        }
        vt_pair_store((unsigned int*)VtBuf, vr, scc, va0, vb0, 32);
    }
    __syncthreads();

    for (int t = 0; t < 9; t++) {
        const int cur = t & 1;
        const unsigned short* KsC = KsBuf + cur * 4096;
        const unsigned short* VtC = VtBuf + cur * 4096;

        // issue-early: next tile's V loads (regs) + K DMA (other buffer)
        uint4 va, vb;
        if (t < 8) {
            const int ks0 = t * 64;   // tile t+1 covers keys [t*64, t*64+64)
            va = *(const uint4*)&vp[(size_t)(ks0 + vr) * DHD + scc];
            vb = *(const uint4*)&vp[(size_t)(ks0 + vr + 1) * DHD + scc];
            #pragma unroll
            for (int p = 0; p < 2; p++)
                async_cp16(&kp[(size_t)(ks0 + p * 32 + arow) * DHD + agc],
                           &KsBuf[(cur ^ 1) * 4096 + p * 2048 + wave * 512]);
        }

        // QK^T: scores already in log2 domain (q pre-scaled, wmask pre-scaled)
        f32x16 scA, scB;
        #pragma unroll
        for (int kt = 0; kt < 2; kt++) {
            f32x16 cc;
            #pragma unroll
            for (int j = 0; j < 16; j++) cc[j] = 0.f;
            if (kt == 0 || t > 0) {
                #pragma unroll
                for (int kb = 0; kb < 4; kb++) {
                    const int key = kt * 32 + l31;
                    bf16x8 kf = *(const bf16x8*)&KsC[key * 64 + (((kb * 2 + h8) ^ (key & 7)) << 3)];
                    cc = __builtin_amdgcn_mfma_f32_32x32x16_bf16(kf, qf[kb], cc, 0, 0, 0);
                }
                // lane: q=l31; reg rr -> key = kt*32 + (rr&3) + 8*(rr>>2) + 4*h8
                if (t > 0) {
                    #pragma unroll
                    for (int rg = 0; rg < 4; rg++) {
                        uint2 mu = *(const uint2*)&wmask[b * SS + (t - 1) * 64 + kt * 32 + rg * 8 + 4 * h8];
                        const unsigned short* mp = (const unsigned short*)&mu;
                        #pragma unroll
                        for (int r = 0; r < 4; r++)
                            cc[rg * 4 + r] += b2f(mp[r]);
                    }
                } else {
                    #pragma unroll
                    for (int j = 8; j < 16; j++) cc[j] = -1e30f;  // keys 16..31 absent
                }
            } else {
                #pragma unroll
                for (int j = 0; j < 16; j++) cc[j] = -1e30f;      // t==0: keys 32..63 absent
            }
            if (kt == 0) scA = cc; else scB = cc;
        }

        // online softmax, exp2 domain, exact defer-max
        float mx = -1e30f;
        #pragma unroll
        for (int j = 0; j < 16; j++) mx = fmaxf(mx, scA[j]);
        #pragma unroll
        for (int j = 0; j < 16; j++) mx = fmaxf(mx, scB[j]);
        mx = fmaxf(mx, __shfl_xor(mx, 32, 64));
        if (!__all(mx <= m_s)) {
            const float mn = fmaxf(m_s, mx);
            const float alpha = ex2(m_s - mn);
            m_s = mn;
            l_s *= alpha;
            #pragma unroll
            for (int mb = 0; mb < 2; mb++)
                #pragma unroll
                for (int j = 0; j < 16; j++) oacc[mb][j] *= alpha;
        }
        float rs = 0.f;
        #pragma unroll
        for (int j = 0; j < 16; j++) { float pw = ex2(scA[j] - m_s); scA[j] = pw; rs += pw; }
        #pragma unroll
        for (int j = 0; j < 16; j++) { float pw = ex2(scB[j] - m_s); scB[j] = pw; rs += pw; }
        rs += __shfl_xor(rs, 32, 64);
        l_s += rs;

        // PV with in-register P via cvt_pk + permlane32_swap
        #pragma unroll
        for (int kt = 0; kt < 2; kt++) {
            unsigned int wA[4], wB[4];
            #pragma unroll
            for (int g = 0; g < 4; g++) {
                const float s0 = (kt == 0) ? scA[4 * g + 0] : scB[4 * g + 0];
                const float s1 = (kt == 0) ? scA[4 * g + 1] : scB[4 * g + 1];
                const float s2 = (kt == 0) ? scA[4 * g + 2] : scB[4 * g + 2];
                const float s3 = (kt == 0) ? scA[4 * g + 3] : scB[4 * g + 3];
                wA[g] = pk2(s0, s1);
                wB[g] = pk2(s2, s3);
            }
            #pragma unroll
            for (int kb = 0; kb < 2; kb++) {
                auto ra  = __builtin_amdgcn_permlane32_swap(wA[2 * kb], wA[2 * kb + 1], false, false);
                auto rbp = __builtin_amdgcn_permlane32_swap(wB[2 * kb], wB[2 * kb + 1], false, false);
                union { unsigned int u[4]; bf16x8 v8; } pfu;
                pfu.u[0] = (unsigned int)ra[0];
                pfu.u[1] = (unsigned int)rbp[0];
                pfu.u[2] = (unsigned int)ra[1];
                pfu.u[3] = (unsigned int)rbp[1];
                const int kb2 = kt * 2 + kb;
                #pragma unroll
                for (int mb = 0; mb < 2; mb++) {
                    const int d = mb * 32 + l31;
                    bf16x8 vf = *(const bf16x8*)&VtC[d * 64 + (((kb2 * 2 + h8) ^ ((d >> 3) & 7)) << 3)];
                    oacc[mb] = __builtin_amdgcn_mfma_f32_32x32x16_bf16(vf, pfu.v8, oacc[mb], 0, 0, 0);
                }
            }
        }

        // write-late: V tile t+1 into the other buffer, then one barrier
        if (t < 8) {
            vt_pair_store((unsigned int*)(VtBuf + (cur ^ 1) * 4096), vr, scc, va, vb, 32);
            __syncthreads();
        }
    }

    // epilogue: q = q0+l31; reg rr of mb -> d = mb*32 + (rr&3) + 8*(rr>>2) + 4*h8
    const float inv = 1.f / l_s;
    const int s = q0 + l31;
    #pragma unroll
    for (int mb = 0; mb < 2; mb++) {
        #pragma unroll
        for (int rg = 0; rg < 4; rg++) {
            const int d0 = mb * 32 + rg * 8 + 4 * h8;
            const size_t idx = ((size_t)b * SS + s) * DM + h * DHD + d0;
            if (isf32) {
                float4 o4;
                o4.x = oacc[mb][rg * 4 + 0] * inv;
                o4.y = oacc[mb][rg * 4 + 1] * inv;
                o4.z = oacc[mb][rg * 4 + 2] * inv;
                o4.w = oacc[mb][rg * 4 + 3] * inv;
                *(float4*)&((float*)out)[idx] = o4;
            } else {
                uint2 o2;
                o2.x = pk2(oacc[mb][rg * 4 + 0] * inv, oacc[mb][rg * 4 + 1] * inv);
                o2.y = pk2(oacc[mb][rg * 4 + 2] * inv, oacc[mb][rg * 4 + 3] * inv);
                *(uint2*)&((unsigned short*)out)[idx] = o2;
            }
        }
    }
}

// ---------------------------------------------------------------------------
extern "C" void kernel_launch(void* const* d_in, const int* in_sizes, int n_in,
                              void* d_out, int out_size, void* d_ws, size_t ws_size,
                              hipStream_t stream) {
    const void* hs   = d_in[0];
    const void* mask = d_in[1];
    const void* gte  = d_in[2];
    const void* Wq   = d_in[3];
    const void* bq   = d_in[4];
    const void* Wk   = d_in[5];
    const void* bk   = d_in[6];
    const void* Wv   = d_in[7];
    const void* bv   = d_in[8];

    const size_t qkv_sz = (size_t)BB * NH * SS * DHD;
    const size_t g_sz   = (size_t)RBATCH * NH * GG * DHD;
    const size_t msk_sz = (size_t)BB * SS;
    const size_t x_sz   = (size_t)XROWS * DM;
    const size_t wt_sz  = (size_t)NALL * DM;
    const size_t ba_sz  = (size_t)NALL;
    const size_t need_hw = 3 * qkv_sz + 3 * g_sz + msk_sz + x_sz + wt_sz + ba_sz;
    if (ws_size < need_hw * 2 + 256) return;

    unsigned short* q     = (unsigned short*)d_ws;
    unsigned short* kk    = q + qkv_sz;
    unsigned short* vv    = kk + qkv_sz;
    unsigned short* gq    = vv + qkv_sz;
    unsigned short* gk    = gq + g_sz;
    unsigned short* gv    = gk + g_sz;
    unsigned short* wmask = gv + g_sz;
    unsigned short* Xb    = wmask + msk_sz;
    unsigned short* Wt    = Xb + x_sz;
    unsigned short* b_all = Wt + wt_sz;
    int* flag = (int*)(b_all + ba_sz);
    int* cnt  = flag + 1;                         // 48 split-k counters
    // partials overlay the (dead after qkv_gemm) Xb region
    float* Opart = (float*)Xb;
    float* Mpart = Opart + (size_t)NSPLIT * RBATCH * NH * 1024;
    float* Lpart = Mpart + (size_t)NSPLIT * RBATCH * NH * 16;

    cvt_xw<<<CVT_XBLKS + CVT_WBLKS, 256, 0, stream>>>(
        hs, gte, bq, bk, bv, mask, Wq, Wk, Wv, Xb, b_all, wmask, Wt, flag, cnt);

    qkv_gemm<<<dim3(QKV_NWG), 256, 0, stream>>>(Xb, Wt, b_all, q, kk, vv, gq, gk, gv);

    attn_fused<<<dim3(GS_NWG + AL_NWG), 256, 0, stream>>>(
        q, kk, vv, gq, gk, gv, wmask, flag, d_out, Opart, Mpart, Lpart, cnt);
}

// Round 13
// 315.159 us; speedup vs baseline: 1.0105x; 1.0105x over previous
//
#include <hip/hip_runtime.h>
#include <hip/hip_bf16.h>
#include <stdint.h>

#define NH 12
#define DHD 64
#define DM 768
#define BB 32
#define SS 512
#define GG 16
#define NCTX 8
#define RBATCH 4
#define NSPLIT 4
#define OUTG_OFF ((size_t)BB * SS * DM)

#define XROWS 16512            // 16384 hs + 64 gte + 64 zero pad
#define NALL 2304              // 3*768 concat Q|K|V output cols
#define NX8 (XROWS * DM / 8)
#define NB8 (NALL / 8)
#define NM8 (BB * SS / 8)

#define LOG2E 1.4426950408889634f
#define QSCALE 0.18033688011112042f   // 0.125 * log2(e)

typedef __bf16 bf16x8 __attribute__((ext_vector_type(8)));
typedef float f32x4 __attribute__((ext_vector_type(4)));
typedef float f32x16 __attribute__((ext_vector_type(16)));

__device__ __forceinline__ float b2f(unsigned short u) {
    union { unsigned int i; float f; } x;
    x.i = ((unsigned int)u) << 16;
    return x.f;
}
__device__ __forceinline__ unsigned short f2b(float f) {
    __hip_bfloat16 h = __float2bfloat16(f);
    return *reinterpret_cast<unsigned short*>(&h);
}
__device__ __forceinline__ unsigned int pk2(float a, float b) {
    return ((unsigned int)f2b(b) << 16) | (unsigned int)f2b(a);
}
__device__ __forceinline__ float ex2(float x) {
    return __builtin_amdgcn_exp2f(x);
}
__device__ __forceinline__ float ldv(const void* p, size_t i, int isf32) {
    return isf32 ? ((const float*)p)[i] : b2f(((const unsigned short*)p)[i]);
}
__device__ __forceinline__ void stv(void* p, size_t i, int isf32, float v) {
    if (isf32) ((float*)p)[i] = v;
    else       ((unsigned short*)p)[i] = f2b(v);
}
// async global->LDS, 16B per lane; LDS dest = wave-uniform base + lane*16
__device__ __forceinline__ void async_cp16(const unsigned short* g, unsigned short* l) {
    __builtin_amdgcn_global_load_lds(
        (const __attribute__((address_space(1))) unsigned int*)g,
        (__attribute__((address_space(3))) unsigned int*)l, 16, 0, 0);
}

// Transposed V store: rows (vr, vr+1) x cols [scc, scc+8) packed pairwise with
// v_perm into u32 writes. Layout (u16 view): Vt[d*2*ldq + swz8 + (key&7)],
// swz8 = ((key>>3)^((d>>3)&7))<<3 — identical to the scalar-store layout.
__device__ __forceinline__ void vt_pair_store(unsigned int* Vt32, int vr, int scc,
                                              uint4 a, uint4 b, int ldq) {
    const unsigned int* au = (const unsigned int*)&a;
    const unsigned int* bu = (const unsigned int*)&b;
    #pragma unroll
    for (int i = 0; i < 4; i++) {
        const int d0 = scc + 2 * i;
        const int swz = ((vr >> 3) ^ ((d0 >> 3) & 7));
        const int i32 = d0 * ldq + (swz << 2) + ((vr & 7) >> 1);
        Vt32[i32]       = __builtin_amdgcn_perm(bu[i], au[i], 0x05040100u);
        Vt32[i32 + ldq] = __builtin_amdgcn_perm(bu[i], au[i], 0x07060302u);
    }
}

// ---------------------------------------------------------------------------
// cvt_xw: fused cvt_x + cvt_w, with INLINE per-block dtype detection on Wq
// (sigma=0.02, never exactly 0). Block 0 writes *flag for the attn kernels.
// Blocks [0, CVT_XBLKS): X_bf16[16512][768] = [hs ; gte ; zeros], bias_all,
// wmask pre-scaled by log2(e). Blocks [CVT_XBLKS, +432): Wt transpose.
// ---------------------------------------------------------------------------
#define CVT_ITEMS (NX8 + NB8 + NM8)
#define CVT_XBLKS ((CVT_ITEMS + 255) / 256)
#define CVT_WBLKS (12 * 36)
__global__ __launch_bounds__(256) void cvt_xw(
    const void* __restrict__ hs, const void* __restrict__ gte,
    const void* __restrict__ bq, const void* __restrict__ bk,
    const void* __restrict__ bv, const void* __restrict__ mask,
    const void* __restrict__ Wq, const void* __restrict__ Wk,
    const void* __restrict__ Wv,
    unsigned short* __restrict__ Xb, unsigned short* __restrict__ b_all,
    unsigned short* __restrict__ wmask, unsigned short* __restrict__ Wt,
    int* __restrict__ flag)
{
    __shared__ float T[64][65];
    __shared__ int redhi, redzz;
    const int tid = threadIdx.x;

    // inline dtype detection (L2-hot after the first block; ~16 dword loads)
    {
        const unsigned short* wq16 = (const unsigned short*)Wq;
        int lh = 0, lz = 0;
        for (int i = tid; i < 4096; i += 256) {
            unsigned short u = wq16[2 * i];
            if (((u >> 7) & 0xFF) >= 130) lh++;
            if (u == 0) lz++;
        }
        if (tid == 0) { redhi = 0; redzz = 0; }
        __syncthreads();
        #pragma unroll
        for (int off = 32; off; off >>= 1) {
            lh += __shfl_down(lh, off, 64);
            lz += __shfl_down(lz, off, 64);
        }
        if ((tid & 63) == 0) { atomicAdd(&redhi, lh); atomicAdd(&redzz, lz); }
        __syncthreads();
    }
    const int isf32 = (redhi > 512 || redzz > 3500) ? 1 : 0;
    if (blockIdx.x == 0 && tid == 0) *flag = isf32;

    if (blockIdx.x < CVT_XBLKS) {
        const int e = blockIdx.x * 256 + tid;
        if (e < NX8) {
            const int base = e * 8;
            const int row = base / DM, col = base % DM;
            unsigned short o8[8];
            if (row < 16384) {
                if (isf32) {
                    float4 a = ((const float4*)hs)[e * 2];
                    float4 c = ((const float4*)hs)[e * 2 + 1];
                    o8[0]=f2b(a.x); o8[1]=f2b(a.y); o8[2]=f2b(a.z); o8[3]=f2b(a.w);
                    o8[4]=f2b(c.x); o8[5]=f2b(c.y); o8[6]=f2b(c.z); o8[7]=f2b(c.w);
                } else {
                    *(uint4*)o8 = ((const uint4*)hs)[e];
                }
            } else if (row < 16448) {
                size_t soff = (size_t)(row - 16384) * DM + col;
                #pragma unroll
                for (int i = 0; i < 8; i++) o8[i] = f2b(ldv(gte, soff + i, isf32));
            } else {
                #pragma unroll
                for (int i = 0; i < 8; i++) o8[i] = 0;
            }
            *(uint4*)&Xb[base] = *(const uint4*)o8;
        } else if (e < NX8 + NB8) {
            const int i0 = (e - NX8) * 8;
            #pragma unroll
            for (int i = 0; i < 8; i++) {
                int ng = i0 + i;
                int z = ng / DM;
                const void* src = (z == 0) ? bq : (z == 1) ? bk : bv;
                b_all[ng] = f2b(ldv(src, ng % DM, isf32));
            }
        } else if (e < NX8 + NB8 + NM8) {
            const int i0 = (e - NX8 - NB8) * 8;
            #pragma unroll
            for (int i = 0; i < 8; i++)
                wmask[i0 + i] = f2b(ldv(mask, i0 + i, isf32) * LOG2E);
        }
    } else {
        const int widx = blockIdx.x - CVT_XBLKS;
        const int kt = widx % 12;
        const int ngt = widx / 12;
        const int z = ngt / 12, nt = ngt % 12;
        const void* W = (z == 0) ? Wq : (z == 1) ? Wk : Wv;

        for (int jj = 0; jj < 16; jj++) {
            int el = tid + jj * 256;
            int r = el >> 6, c = el & 63;
            T[r][c] = ldv(W, (size_t)(kt * 64 + r) * DM + nt * 64 + c, isf32);
        }
        __syncthreads();
        for (int jj = 0; jj < 16; jj++) {
            int el = tid + jj * 256;
            int rn = el >> 6, ck = el & 63;
            Wt[(size_t)(z * DM + nt * 64 + rn) * DM + kt * 64 + ck] = f2b(T[ck][rn]);
        }
    }
}

// ---------------------------------------------------------------------------
// Fused QKV GEMM v4 (round-5 proven, 103.3 us): 128x128 tile, pair-window
// double buffer — each window stages TWO BK=32 k-tiles (8 async_cp16) and
// computes 32 MFMAs, 12 __syncthreads drains instead of 24.
// XCD-chunked nt-fast swizzle; operand-swapped MFMA epilogue (uint2 stores).
// ---------------------------------------------------------------------------
#define QKV_NWG (129 * 18)
__global__ __launch_bounds__(256) void qkv_gemm(
    const unsigned short* __restrict__ Xb,
    const unsigned short* __restrict__ Wt,
    const unsigned short* __restrict__ b_all,
    unsigned short* __restrict__ q, unsigned short* __restrict__ kk_,
    unsigned short* __restrict__ v,
    unsigned short* __restrict__ gq, unsigned short* __restrict__ gk,
    unsigned short* __restrict__ gv)
{
    __shared__ __align__(16) unsigned short As[2][2][128 * 32];
    __shared__ __align__(16) unsigned short Bs[2][2][128 * 32];

    const int orig = blockIdx.x;
    const int q8 = QKV_NWG >> 3, r8 = QKV_NWG & 7;
    const int xcd = orig & 7, lin = orig >> 3;
    const int swz = (xcd < r8 ? xcd * (q8 + 1) : r8 * (q8 + 1) + (xcd - r8) * q8) + lin;
    const int mt = swz / 18, nt = swz - mt * 18;

    const int tid = threadIdx.x;
    const int wave = tid >> 6, lane = tid & 63;
    const int quad = lane >> 4, l16 = lane & 15;
    const int wm = wave & 1, wn = wave >> 1;
    const int z = nt / 6;
    unsigned short* YL = (z == 0) ? q : (z == 1) ? kk_ : v;
    unsigned short* YG = (z == 0) ? gq : (z == 1) ? gk : gv;
    const float qsc = (z == 0) ? QSCALE : 1.0f;

    const int sr = tid >> 2, sc = (tid & 3) * 8;  // LDS slot = tid*16B

    const unsigned short* Arow0 = &Xb[(size_t)(mt * 128 + sr) * DM + sc];
    const unsigned short* Arow1 = Arow0 + (size_t)64 * DM;
    const unsigned short* Brow0 = &Wt[(size_t)(nt * 128 + sr) * DM + sc];
    const unsigned short* Brow1 = Brow0 + (size_t)64 * DM;

    f32x4 acc[4][4];
    #pragma unroll
    for (int i = 0; i < 4; i++)
        for (int j = 0; j < 4; j++)
            for (int r = 0; r < 4; r++) acc[i][j][r] = 0.f;

    // stage k-tile pair p (tiles 2p, 2p+1) into buffer bb
#define QKV_STAGE_PAIR(p, bb) do {                                       \
        const int k0_ = (p) * 64;                                        \
        async_cp16(Arow0 + k0_,      &As[(bb)][0][wave * 512]);          \
        async_cp16(Arow1 + k0_,      &As[(bb)][0][2048 + wave * 512]);   \
        async_cp16(Brow0 + k0_,      &Bs[(bb)][0][wave * 512]);          \
        async_cp16(Brow1 + k0_,      &Bs[(bb)][0][2048 + wave * 512]);   \
        async_cp16(Arow0 + k0_ + 32, &As[(bb)][1][wave * 512]);          \
        async_cp16(Arow1 + k0_ + 32, &As[(bb)][1][2048 + wave * 512]);   \
        async_cp16(Brow0 + k0_ + 32, &Bs[(bb)][1][wave * 512]);          \
        async_cp16(Brow1 + k0_ + 32, &Bs[(bb)][1][2048 + wave * 512]);   \
    } while (0)

    // prologue: stage pair 0 into buffer 0
    QKV_STAGE_PAIR(0, 0);
    __syncthreads();

    int cur = 0;
    for (int p = 0; p < 12; p++) {
        // prefetch next pair into the other buffer (hidden under 32 MFMAs)
        if (p < 11) QKV_STAGE_PAIR(p + 1, cur ^ 1);

        #pragma unroll
        for (int sub = 0; sub < 2; sub++) {
            bf16x8 af[4], bf[4];
            #pragma unroll
            for (int ib = 0; ib < 4; ib++)
                af[ib] = *(const bf16x8*)&As[cur][sub][(wm * 64 + ib * 16 + l16) * 32 + quad * 8];
            #pragma unroll
            for (int jb = 0; jb < 4; jb++)
                bf[jb] = *(const bf16x8*)&Bs[cur][sub][(wn * 64 + jb * 16 + l16) * 32 + quad * 8];
            // operand-swapped: C rows = output channels (ng), C cols = X rows (m)
            #pragma unroll
            for (int ib = 0; ib < 4; ib++)
                #pragma unroll
                for (int jb = 0; jb < 4; jb++)
                    acc[ib][jb] = __builtin_amdgcn_mfma_f32_16x16x32_bf16(
                        bf[jb], af[ib], acc[ib][jb], 0, 0, 0);
        }

        if (p < 11) __syncthreads();
        cur ^= 1;
    }
#undef QKV_STAGE_PAIR

    // epilogue: lane holds m = ...+l16 (fixed), 4 consecutive ng per acc reg
    #pragma unroll
    for (int ib = 0; ib < 4; ib++) {
        const int m = mt * 128 + wm * 64 + ib * 16 + l16;
        if (m >= 16448) continue;
        const bool loc = (m < 16384);
        const int b = m >> 9, s = m & 511;
        const int gl = m - 16384;
        const int rbx = gl >> 4, g = gl & 15;
        #pragma unroll
        for (int jb = 0; jb < 4; jb++) {
            const int ng0 = nt * 128 + wn * 64 + jb * 16 + quad * 4;
            const int o = ng0 - z * DM;
            const int h = o >> 6, dh0 = o & 63;
            const uint2 bu = *(const uint2*)&b_all[ng0];
            const unsigned short* bp = (const unsigned short*)&bu;
            const float y0 = (acc[ib][jb][0] + b2f(bp[0])) * qsc;
            const float y1 = (acc[ib][jb][1] + b2f(bp[1])) * qsc;
            const float y2 = (acc[ib][jb][2] + b2f(bp[2])) * qsc;
            const float y3 = (acc[ib][jb][3] + b2f(bp[3])) * qsc;
            uint2 o2;
            o2.x = pk2(y0, y1);
            o2.y = pk2(y2, y3);
            if (loc) {
                *(uint2*)&YL[(((size_t)b * NH + h) * SS + s) * DHD + dh0] = o2;
            } else {
                *(uint2*)&YG[(((size_t)rbx * NH + h) * GG + g) * DHD + dh0] = o2;
            }
        }
    }
}

// ---------------------------------------------------------------------------
// attn_fused v2: gsplit blocks [0, GS_NWG) + local blocks [GS_NWG, +AL_NWG).
// LDS union cut 40.5 -> 32 KiB: gsplit's Ps (8 KiB) now OVERLAYS Ks, legal
// because Ks is dead after the QK^T phase of each tile; a uniform mid-tile
// barrier separates the last Ks read from the first Ps write (the former
// `continue` for inactive gtile waves is now predication so the barrier is
// non-divergent). Round-12 counters: Occupancy 19% @ 41472B LDS (3 blk/CU,
// latency-bound, VALU 47/Mfma 11) -> 32768B allows 4-5 blk/CU.
// Semaphore merge reverted (round-12: neutral); separate gmerge dispatch.
// ---------------------------------------------------------------------------
#define GS_NWG (NH * RBATCH * NSPLIT)   // 192
#define AL_NWG (4 * NH * BB)            // 1536, divisible by 8
__global__ __launch_bounds__(256) void attn_fused(
    const unsigned short* __restrict__ q,
    const unsigned short* __restrict__ k,
    const unsigned short* __restrict__ v,
    const unsigned short* __restrict__ gq,
    const unsigned short* __restrict__ gk,
    const unsigned short* __restrict__ gv,
    const unsigned short* __restrict__ wmask,
    const int* __restrict__ flag,
    void* __restrict__ out,
    float* __restrict__ Opart, float* __restrict__ Mpart,
    float* __restrict__ Lpart)
{
    __shared__ __align__(16) unsigned short SMEM[16384];   // 32 KiB union

    const int tid = threadIdx.x, wave = tid >> 6, lane = tid & 63;
    const int sr = tid >> 3, scc = (tid & 7) * 8;
    const int vr = sr * 2;
    const int agc = (((lane & 7) ^ ((lane >> 3) & 7)) << 3);
    const int arow = 8 * wave + (lane >> 3);

    if (blockIdx.x < GS_NWG) {
        // ===== gsplit path: Ks 16K @0, Vt 16K @16K, Ps 8K overlays Ks ======
        unsigned short* Ks = SMEM;                    // 128*64 u16 = 16 KiB
        unsigned short* Vt = SMEM + 8192;             // 64*128 u16 = 16 KiB
        unsigned short* Ps = SMEM;                    // overlays Ks[0:8KiB]
        unsigned int* Vt32 = (unsigned int*)Vt;

        const int idx = blockIdx.x;
        const int h = idx % NH;
        const int rb = (idx / NH) % RBATCH;
        const int sp = idx / (NH * RBATCH);
        const int quad = lane >> 4, l16 = lane & 15;

        const size_t gbh = (size_t)rb * NH + h;
        const unsigned short* gqp = gq + gbh * GG * DHD;
        const unsigned short* gkp = gk + gbh * GG * DHD;
        const unsigned short* gvp = gv + gbh * GG * DHD;

        bf16x8 aq[2];
        aq[0] = *(const bf16x8*)&gqp[l16 * DHD + quad * 8];
        aq[1] = *(const bf16x8*)&gqp[l16 * DHD + 32 + quad * 8];

        f32x4 oacc[4];
        #pragma unroll
        for (int db = 0; db < 4; db++)
            for (int r = 0; r < 4; r++) oacc[db][r] = 0.f;
        float m_s = -1e30f, l_s = 0.f;

        unsigned short* myP = &Ps[wave * 1024];

        const int ntt = (sp == 0) ? 9 : 8;
        for (int ti = 0; ti < ntt; ti++) {
            const bool gtile = (sp == 0 && ti == 0);
            const bool active = !(gtile && wave != 0);
            int cb = 0, soff = 0;
            __syncthreads();
            if (gtile) {
                if (sr < 16) {
                    uint4 kx = *(const uint4*)&gkp[sr * DHD + scc];
                    *(uint4*)&Ks[sr * 64 + (((scc >> 3) ^ (sr & 7)) << 3)] = kx;
                    uint4 va = {0, 0, 0, 0}, vb = {0, 0, 0, 0};
                    if (sr < 8) {
                        va = *(const uint4*)&gvp[vr * DHD + scc];
                        vb = *(const uint4*)&gvp[(vr + 1) * DHD + scc];
                    }
                    vt_pair_store(Vt32, vr, scc, va, vb, 64);
                } else {
                    uint4 zz4 = {0, 0, 0, 0};
                    *(uint4*)&Ks[sr * 64 + (((scc >> 3) ^ (sr & 7)) << 3)] = zz4;
                }
            } else {
                const int kidx = sp * 1024 + (ti - ((sp == 0) ? 1 : 0)) * 128;
                cb = rb * NCTX + (kidx >> 9);
                soff = kidx & 511;
                const unsigned short* kp = k + ((size_t)cb * NH + h) * SS * DHD;
                const unsigned short* vp = v + ((size_t)cb * NH + h) * SS * DHD;
                #pragma unroll
                for (int p = 0; p < 4; p++)
                    async_cp16(&kp[(size_t)(soff + p * 32 + arow) * DHD + agc],
                               &Ks[p * 2048 + wave * 512]);
                #pragma unroll
                for (int pp = 0; pp < 2; pp++) {
                    const int vrr = vr + pp * 64;
                    uint4 va = *(const uint4*)&vp[(size_t)(soff + vrr) * DHD + scc];
                    uint4 vb = *(const uint4*)&vp[(size_t)(soff + vrr + 1) * DHD + scc];
                    vt_pair_store(Vt32, vrr, scc, va, vb, 64);
                }
            }
            __syncthreads();

            // ---- phase 1: QK^T + online softmax (reads Ks; no Ps writes) ---
            const int nbn = gtile ? 1 : 2;
            f32x4 c[2];
            if (active) {
                for (int hh = 0; hh < nbn; hh++) {
                    f32x4 cc = {0.f, 0.f, 0.f, 0.f};
                    const int key = wave * 32 + hh * 16 + l16;
                    #pragma unroll
                    for (int kd = 0; kd < 2; kd++) {
                        bf16x8 kf = *(const bf16x8*)&Ks[key * 64 + (((kd * 4 + quad) ^ (key & 7)) << 3)];
                        cc = __builtin_amdgcn_mfma_f32_16x16x32_bf16(kf, aq[kd], cc, 0, 0, 0);
                    }
                    if (!gtile) {
                        uint2 mu = *(const uint2*)&wmask[cb * SS + soff + wave * 32 + hh * 16 + quad * 4];
                        const unsigned short* mp = (const unsigned short*)&mu;
                        #pragma unroll
                        for (int r = 0; r < 4; r++)
                            cc[r] += b2f(mp[r]);
                    }
                    c[hh] = cc;
                }

                float mx = -1e30f;
                for (int hh = 0; hh < nbn; hh++)
                    #pragma unroll
                    for (int r = 0; r < 4; r++) mx = fmaxf(mx, c[hh][r]);
                mx = fmaxf(mx, __shfl_xor(mx, 16, 64));
                mx = fmaxf(mx, __shfl_xor(mx, 32, 64));
                const float mn = fmaxf(m_s, mx);
                const float alpha = ex2(m_s - mn);
                m_s = mn;
                float rs = 0.f;
                for (int hh = 0; hh < nbn; hh++)
                    #pragma unroll
                    for (int r = 0; r < 4; r++) {
                        float p = ex2(c[hh][r] - mn);
                        c[hh][r] = p;
                        rs += p;
                    }
                rs += __shfl_xor(rs, 16, 64);
                rs += __shfl_xor(rs, 32, 64);
                l_s = l_s * alpha + rs;
                #pragma unroll
                for (int db = 0; db < 4; db++)
                    for (int r = 0; r < 4; r++) oacc[db][r] *= alpha;
            }

            // uniform barrier: last Ks read is above, first Ps write below
            __syncthreads();

            // ---- phase 2: P^T store (into Ks-overlay) + PV ----------------
            if (active) {
                for (int hh = 0; hh < nbn; hh++) {
                    uint2 pw;
                    pw.x = pk2(c[hh][0], c[hh][1]);
                    pw.y = pk2(c[hh][2], c[hh][3]);
                    const int cch = ((hh * 2 + (quad >> 1)) ^ (l16 & 7));
                    *(uint2*)&myP[l16 * 64 + cch * 8 + (quad & 1) * 4] = pw;
                }
                if (nbn == 1) {
                    uint2 zz2; zz2.x = 0; zz2.y = 0;
                    const int cch = ((2 + (quad >> 1)) ^ (l16 & 7));
                    *(uint2*)&myP[l16 * 64 + cch * 8 + (quad & 1) * 4] = zz2;
                }

                bf16x8 pf = *(const bf16x8*)&myP[l16 * 64 + ((quad ^ (l16 & 7)) << 3)];
                #pragma unroll
                for (int db = 0; db < 4; db++) {
                    const int d = db * 16 + l16;
                    const int kc = wave * 4 + quad;
                    bf16x8 vf = *(const bf16x8*)&Vt[d * 128 + ((kc ^ ((d >> 3) & 7)) << 3)];
                    oacc[db] = __builtin_amdgcn_mfma_f32_16x16x32_bf16(vf, pf, oacc[db], 0, 0, 0);
                }
            }
        }

        // intra-block merge of 4 waves, then write split partial
        // Om [4][16][64] f32 = 16 KiB over Ks region; Mw/Lw over Vt region
        __syncthreads();
        float* Om = (float*)Ks;
        float* Mw = (float*)Vt;
        float* Lw = Mw + 64;
        const int quad2 = lane >> 4, l162 = lane & 15;
        #pragma unroll
        for (int db = 0; db < 4; db++)
            for (int r = 0; r < 4; r++)
                Om[(wave * 16 + l162) * 64 + db * 16 + quad2 * 4 + r] = oacc[db][r];
        if (quad2 == 0) {
            Mw[wave * 16 + l162] = m_s;
            Lw[wave * 16 + l162] = l_s;
        }
        __syncthreads();

        const size_t pbase = ((size_t)(sp * RBATCH + rb) * NH + h) * 1024;
        for (int e = tid; e < 1024; e += 256) {
            const int qrow = e >> 6, d = e & 63;
            float M = fmaxf(fmaxf(Mw[qrow], Mw[16 + qrow]), fmaxf(Mw[32 + qrow], Mw[48 + qrow]));
            float acc = 0.f, L = 0.f;
            #pragma unroll
            for (int w = 0; w < 4; w++) {
                float scw = ex2(Mw[w * 16 + qrow] - M);
                acc += Om[(w * 16 + qrow) * 64 + d] * scw;
                L += Lw[w * 16 + qrow] * scw;
            }
            Opart[pbase + e] = acc;
            if (d == 0) {
                Mpart[((sp * RBATCH + rb) * NH + h) * 16 + qrow] = M;
                Lpart[((sp * RBATCH + rb) * NH + h) * 16 + qrow] = L;
            }
        }
        return;
    }

    // ================= local path (round-8 v6 body, 32 KiB) =================
    unsigned short* KsBuf = SMEM;          // [2][64*64] = 16 KiB
    unsigned short* VtBuf = SMEM + 8192;   // [2][64*64] = 16 KiB

    const int orig = blockIdx.x - GS_NWG;
    const int swz = (orig & 7) * (AL_NWG / 8) + (orig >> 3);
    const int qt = swz & 3;
    const int hb = swz >> 2;
    const int h = hb % NH, b = hb / NH;

    const int rb = b >> 3;
    const int l31 = lane & 31, h8 = lane >> 5;
    const int isf32 = *flag;
    const int q0 = qt * 128 + wave * 32;

    const size_t bh = (size_t)b * NH + h;
    const unsigned short* qp = q + bh * SS * DHD;
    const unsigned short* kp = k + bh * SS * DHD;
    const unsigned short* vp = v + bh * SS * DHD;
    const size_t gbh = (size_t)rb * NH + h;
    const unsigned short* gkp = gk + gbh * GG * DHD;
    const unsigned short* gvp = gv + gbh * GG * DHD;

    // Q fragments (MFMA B-operand): B[k][n]: n=q=l31, k = kb*16 + h8*8 + j
    bf16x8 qf[4];
    #pragma unroll
    for (int kb = 0; kb < 4; kb++)
        qf[kb] = *(const bf16x8*)&qp[(size_t)(q0 + l31) * DHD + kb * 16 + h8 * 8];

    f32x16 oacc[2];
    #pragma unroll
    for (int mb = 0; mb < 2; mb++)
        #pragma unroll
        for (int j = 0; j < 16; j++) oacc[mb][j] = 0.f;
    float m_s = -1e30f, l_s = 0.f;

    // prologue: stage tile 0 (16 global keys + zero pad) into buffer 0
    if (sr < 16) {
        uint4 kx = *(const uint4*)&gkp[sr * DHD + scc];
        *(uint4*)&KsBuf[sr * 64 + (((scc >> 3) ^ (sr & 7)) << 3)] = kx;
    } else {
        uint4 zz4 = {0, 0, 0, 0};
        *(uint4*)&KsBuf[sr * 64 + (((scc >> 3) ^ (sr & 7)) << 3)] = zz4;
    }
    {
        uint4 va0 = {0, 0, 0, 0}, vb0 = {0, 0, 0, 0};
        if (sr < 8) {
            va0 = *(const uint4*)&gvp[vr * DHD + scc];
            vb0 = *(const uint4*)&gvp[(vr + 1) * DHD + scc];
        }
        vt_pair_store((unsigned int*)VtBuf, vr, scc, va0, vb0, 32);
    }
    __syncthreads();

    for (int t = 0; t < 9; t++) {
        const int cur = t & 1;
        const unsigned short* KsC = KsBuf + cur * 4096;
        const unsigned short* VtC = VtBuf + cur * 4096;

        // issue-early: next tile's V loads (regs) + K DMA (other buffer)
        uint4 va, vb;
        if (t < 8) {
            const int ks0 = t * 64;   // tile t+1 covers keys [t*64, t*64+64)
            va = *(const uint4*)&vp[(size_t)(ks0 + vr) * DHD + scc];
            vb = *(const uint4*)&vp[(size_t)(ks0 + vr + 1) * DHD + scc];
            #pragma unroll
            for (int p = 0; p < 2; p++)
                async_cp16(&kp[(size_t)(ks0 + p * 32 + arow) * DHD + agc],
                           &KsBuf[(cur ^ 1) * 4096 + p * 2048 + wave * 512]);
        }

        // QK^T: scores already in log2 domain (q pre-scaled, wmask pre-scaled)
        f32x16 scA, scB;
        #pragma unroll
        for (int kt = 0; kt < 2; kt++) {
            f32x16 cc;
            #pragma unroll
            for (int j = 0; j < 16; j++) cc[j] = 0.f;
            if (kt == 0 || t > 0) {
                #pragma unroll
                for (int kb = 0; kb < 4; kb++) {
                    const int key = kt * 32 + l31;
                    bf16x8 kf = *(const bf16x8*)&KsC[key * 64 + (((kb * 2 + h8) ^ (key & 7)) << 3)];
                    cc = __builtin_amdgcn_mfma_f32_32x32x16_bf16(kf, qf[kb], cc, 0, 0, 0);
                }
                // lane: q=l31; reg rr -> key = kt*32 + (rr&3) + 8*(rr>>2) + 4*h8
                if (t > 0) {
                    #pragma unroll
                    for (int rg = 0; rg < 4; rg++) {
                        uint2 mu = *(const uint2*)&wmask[b * SS + (t - 1) * 64 + kt * 32 + rg * 8 + 4 * h8];
                        const unsigned short* mp = (const unsigned short*)&mu;
                        #pragma unroll
                        for (int r = 0; r < 4; r++)
                            cc[rg * 4 + r] += b2f(mp[r]);
                    }
                } else {
                    #pragma unroll
                    for (int j = 8; j < 16; j++) cc[j] = -1e30f;  // keys 16..31 absent
                }
            } else {
                #pragma unroll
                for (int j = 0; j < 16; j++) cc[j] = -1e30f;      // t==0: keys 32..63 absent
            }
            if (kt == 0) scA = cc; else scB = cc;
        }

        // online softmax, exp2 domain, exact defer-max
        float mx = -1e30f;
        #pragma unroll
        for (int j = 0; j < 16; j++) mx = fmaxf(mx, scA[j]);
        #pragma unroll
        for (int j = 0; j < 16; j++) mx = fmaxf(mx, scB[j]);
        mx = fmaxf(mx, __shfl_xor(mx, 32, 64));
        if (!__all(mx <= m_s)) {
            const float mn = fmaxf(m_s, mx);
            const float alpha = ex2(m_s - mn);
            m_s = mn;
            l_s *= alpha;
            #pragma unroll
            for (int mb = 0; mb < 2; mb++)
                #pragma unroll
                for (int j = 0; j < 16; j++) oacc[mb][j] *= alpha;
        }
        float rs = 0.f;
        #pragma unroll
        for (int j = 0; j < 16; j++) { float pw = ex2(scA[j] - m_s); scA[j] = pw; rs += pw; }
        #pragma unroll
        for (int j = 0; j < 16; j++) { float pw = ex2(scB[j] - m_s); scB[j] = pw; rs += pw; }
        rs += __shfl_xor(rs, 32, 64);
        l_s += rs;

        // PV with in-register P via cvt_pk + permlane32_swap
        #pragma unroll
        for (int kt = 0; kt < 2; kt++) {
            unsigned int wA[4], wB[4];
            #pragma unroll
            for (int g = 0; g < 4; g++) {
                const float s0 = (kt == 0) ? scA[4 * g + 0] : scB[4 * g + 0];
                const float s1 = (kt == 0) ? scA[4 * g + 1] : scB[4 * g + 1];
                const float s2 = (kt == 0) ? scA[4 * g + 2] : scB[4 * g + 2];
                const float s3 = (kt == 0) ? scA[4 * g + 3] : scB[4 * g + 3];
                wA[g] = pk2(s0, s1);
                wB[g] = pk2(s2, s3);
            }
            #pragma unroll
            for (int kb = 0; kb < 2; kb++) {
                auto ra  = __builtin_amdgcn_permlane32_swap(wA[2 * kb], wA[2 * kb + 1], false, false);
                auto rbp = __builtin_amdgcn_permlane32_swap(wB[2 * kb], wB[2 * kb + 1], false, false);
                union { unsigned int u[4]; bf16x8 v8; } pfu;
                pfu.u[0] = (unsigned int)ra[0];
                pfu.u[1] = (unsigned int)rbp[0];
                pfu.u[2] = (unsigned int)ra[1];
                pfu.u[3] = (unsigned int)rbp[1];
                const int kb2 = kt * 2 + kb;
                #pragma unroll
                for (int mb = 0; mb < 2; mb++) {
                    const int d = mb * 32 + l31;
                    bf16x8 vf = *(const bf16x8*)&VtC[d * 64 + (((kb2 * 2 + h8) ^ ((d >> 3) & 7)) << 3)];
                    oacc[mb] = __builtin_amdgcn_mfma_f32_32x32x16_bf16(vf, pfu.v8, oacc[mb], 0, 0, 0);
                }
            }
        }

        // write-late: V tile t+1 into the other buffer, then one barrier
        if (t < 8) {
            vt_pair_store((unsigned int*)(VtBuf + (cur ^ 1) * 4096), vr, scc, va, vb, 32);
            __syncthreads();
        }
    }

    // epilogue: q = q0+l31; reg rr of mb -> d = mb*32 + (rr&3) + 8*(rr>>2) + 4*h8
    const float inv = 1.f / l_s;
    const int s = q0 + l31;
    #pragma unroll
    for (int mb = 0; mb < 2; mb++) {
        #pragma unroll
        for (int rg = 0; rg < 4; rg++) {
            const int d0 = mb * 32 + rg * 8 + 4 * h8;
            const size_t idx = ((size_t)b * SS + s) * DM + h * DHD + d0;
            if (isf32) {
                float4 o4;
                o4.x = oacc[mb][rg * 4 + 0] * inv;
                o4.y = oacc[mb][rg * 4 + 1] * inv;
                o4.z = oacc[mb][rg * 4 + 2] * inv;
                o4.w = oacc[mb][rg * 4 + 3] * inv;
                *(float4*)&((float*)out)[idx] = o4;
            } else {
                uint2 o2;
                o2.x = pk2(oacc[mb][rg * 4 + 0] * inv, oacc[mb][rg * 4 + 1] * inv);
                o2.y = pk2(oacc[mb][rg * 4 + 2] * inv, oacc[mb][rg * 4 + 3] * inv);
                *(uint2*)&((unsigned short*)out)[idx] = o2;
            }
        }
    }
}

__global__ __launch_bounds__(256) void attn_gmerge(
    const float* __restrict__ Opart, const float* __restrict__ Mpart,
    const float* __restrict__ Lpart, const int* __restrict__ flag,
    void* __restrict__ out)
{
    const int h = blockIdx.x, rb = blockIdx.y;
    const int tid = threadIdx.x;
    const int isf32 = *flag;
    for (int e = tid; e < 1024; e += 256) {
        const int qrow = e >> 6, d = e & 63;
        float M = -1e30f;
        #pragma unroll
        for (int sp = 0; sp < NSPLIT; sp++)
            M = fmaxf(M, Mpart[((sp * RBATCH + rb) * NH + h) * 16 + qrow]);
        float acc = 0.f, L = 0.f;
        #pragma unroll
        for (int sp = 0; sp < NSPLIT; sp++) {
            const size_t pb = ((size_t)(sp * RBATCH + rb) * NH + h);
            float scs = ex2(Mpart[pb * 16 + qrow] - M);
            acc += Opart[pb * 1024 + e] * scs;
            L += Lpart[pb * 16 + qrow] * scs;
        }
        stv(out, OUTG_OFF + ((size_t)rb * GG + qrow) * DM + h * DHD + d, isf32, acc / L);
    }
}

// ---------------------------------------------------------------------------
extern "C" void kernel_launch(void* const* d_in, const int* in_sizes, int n_in,
                              void* d_out, int out_size, void* d_ws, size_t ws_size,
                              hipStream_t stream) {
    const void* hs   = d_in[0];
    const void* mask = d_in[1];
    const void* gte  = d_in[2];
    const void* Wq   = d_in[3];
    const void* bq   = d_in[4];
    const void* Wk   = d_in[5];
    const void* bk   = d_in[6];
    const void* Wv   = d_in[7];
    const void* bv   = d_in[8];

    const size_t qkv_sz = (size_t)BB * NH * SS * DHD;
    const size_t g_sz   = (size_t)RBATCH * NH * GG * DHD;
    const size_t msk_sz = (size_t)BB * SS;
    const size_t x_sz   = (size_t)XROWS * DM;
    const size_t wt_sz  = (size_t)NALL * DM;
    const size_t ba_sz  = (size_t)NALL;
    const size_t need_hw = 3 * qkv_sz + 3 * g_sz + msk_sz + x_sz + wt_sz + ba_sz;
    if (ws_size < need_hw * 2 + 256) return;

    unsigned short* q     = (unsigned short*)d_ws;
    unsigned short* kk    = q + qkv_sz;
    unsigned short* vv    = kk + qkv_sz;
    unsigned short* gq    = vv + qkv_sz;
    unsigned short* gk    = gq + g_sz;
    unsigned short* gv    = gk + g_sz;
    unsigned short* wmask = gv + g_sz;
    unsigned short* Xb    = wmask + msk_sz;
    unsigned short* Wt    = Xb + x_sz;
    unsigned short* b_all = Wt + wt_sz;
    int* flag = (int*)(b_all + ba_sz);
    // partials overlay the (dead after qkv_gemm) Xb region
    float* Opart = (float*)Xb;
    float* Mpart = Opart + (size_t)NSPLIT * RBATCH * NH * 1024;
    float* Lpart = Mpart + (size_t)NSPLIT * RBATCH * NH * 16;

    cvt_xw<<<CVT_XBLKS + CVT_WBLKS, 256, 0, stream>>>(
        hs, gte, bq, bk, bv, mask, Wq, Wk, Wv, Xb, b_all, wmask, Wt, flag);

    qkv_gemm<<<dim3(QKV_NWG), 256, 0, stream>>>(Xb, Wt, b_all, q, kk, vv, gq, gk, gv);

    attn_fused<<<dim3(GS_NWG + AL_NWG), 256, 0, stream>>>(
        q, kk, vv, gq, gk, gv, wmask, flag, d_out, Opart, Mpart, Lpart);
    attn_gmerge<<<dim3(NH, RBATCH), 256, 0, stream>>>(
        Opart, Mpart, Lpart, flag, d_out);
}